// Round 1
// baseline (293.962 us; speedup 1.0000x reference)
//
#include <hip/hip_runtime.h>

#define ROW_LEN 128
#define NPAIR (129 * 129)   // (seq, uniq) pairs, each in [0,128]

// Kernel A: precompute MLP(feats(seq,uniq)) for all 16641 pairs -> table[p][32].
__global__ __launch_bounds__(256) void mlp_table_kernel(
    const float* __restrict__ W1, const float* __restrict__ b1,
    const float* __restrict__ W2, const float* __restrict__ b2,
    float* __restrict__ table)
{
    const int tid = blockIdx.x * 256 + threadIdx.x;
    if (tid >= NPAIR * 32) return;
    const int p = tid >> 5;
    const int j = tid & 31;
    const int seq  = p / 129;
    const int uniq = p % 129;
    const float f0 = (float)seq  * (1.0f / 128.0f);
    const float f1 = (float)uniq * (1.0f / 128.0f);
    const float f2 = (seq > 0) ? ((float)uniq / (float)seq) : 0.0f;

    float acc = b2[j];
    #pragma unroll
    for (int jj = 0; jj < 32; ++jj) {
        float h = b1[jj];                 // lane-uniform -> scalar loads
        h = fmaf(f0, W1[jj],      h);
        h = fmaf(f1, W1[32 + jj], h);
        h = fmaf(f2, W1[64 + jj], h);
        h = fmaxf(h, 0.0f);
        acc = fmaf(h, W2[jj * 32 + j], acc);
    }
    table[tid] = fmaxf(acc, 0.0f);
}

// Kernel B (R6): persistent waves, 32 rows per wave, depth-1 prefetch.
//   - One row per wave per iteration (int2 per lane), 4 waves/block, 16 KB LDS
//     -> 8 blocks/CU = 32 waves/CU, same occupancy as R5.
//   - NEW: grid-stride loop (2048 blocks, 8192 waves) with the NEXT row's
//     id/mask loads issued before processing the current row -> ~900-cycle
//     HBM latency hides under the atomic/ballot/gather of the previous row.
//   - NEW: bitmap fully zeroed ONCE per wave; per row only the <=2 words each
//     active lane set are re-cleared (2 predicated ds_write_b32 vs 4x b128).
//     Safe by same-wave DS instruction ordering (both DS atomic instructions
//     complete before the following ds_write instruction of this wave).
//   - NEW: non-temporal output stores (out is never re-read; keep the 268 MB
//     of inputs resident in L3 instead).
__global__ __launch_bounds__(256, 8) void rows_kernel(
    const int* __restrict__ ids, const int* __restrict__ amask,
    const float* __restrict__ table, float* __restrict__ out, int B)
{
    __shared__ unsigned bm[4][1024];   // one 4 KB bitmap per wave

    const int wave = threadIdx.x >> 6;
    const int lane = threadIdx.x & 63;
    unsigned* mybm = bm[wave];

    // zero own bitmap ONCE: 1024 words = 256 uint4 -> 4 ds_write_b128 per lane
    {
        uint4* z = (uint4*)mybm;
        #pragma unroll
        for (int i = 0; i < 4; ++i) z[lane + i * 64] = make_uint4(0u, 0u, 0u, 0u);
    }

    const long W  = (long)gridDim.x * 4;        // total waves in grid
    long row = (long)blockIdx.x * 4 + wave;
    if (row >= B) return;

    // preload first row: 64 x int2 per row; lane i covers ints [2i, 2i+2)
    int2 id2 = ((const int2*)ids)[row * 64 + lane];
    int2 mk2 = ((const int2*)amask)[row * 64 + lane];

    for (; row < B; row += W) {
        // ---- prefetch next row (clamped addr; value unused on last iter) ----
        const long nrow = (row + W < (long)B) ? (row + W) : row;
        const int2 nid = ((const int2*)ids)[nrow * 64 + lane];
        const int2 nmk = ((const int2*)amask)[nrow * 64 + lane];

        // ---- process current row ----
        int n0 = 0, n1 = 0;                // "new token" flags
        if (mk2.x != 0) {
            const unsigned t = (unsigned)id2.x, m = 1u << (t & 31u);
            n0 = ((atomicOr(&mybm[t >> 5], m) & m) == 0u);
        }
        if (mk2.y != 0) {
            const unsigned t = (unsigned)id2.y, m = 1u << (t & 31u);
            n1 = ((atomicOr(&mybm[t >> 5], m) & m) == 0u);
        }

        // clear only the touched words (every set bit was set by an active
        // lane, and that lane re-zeros its word). Same-wave DS order makes
        // this safe w.r.t. both atomic instructions above and the next
        // iteration's atomics below.
        if (mk2.x != 0) mybm[(unsigned)id2.x >> 5] = 0u;
        if (mk2.y != 0) mybm[(unsigned)id2.y >> 5] = 0u;

        // wave totals purely via ballot + popcount: no DS reduction ops
        const unsigned long long s0 = __ballot(mk2.x != 0);
        const unsigned long long s1 = __ballot(mk2.y != 0);
        const unsigned long long u0 = __ballot(n0 != 0);
        const unsigned long long u1 = __ballot(n1 != 0);

        const int seq  = __popcll(s0) + __popcll(s1);
        const int uniq = __popcll(u0) + __popcll(u1);

        // epilogue: 128B L1/L2-hot table gather, contiguous 128B nt-store
        const int p = seq * 129 + uniq;
        if (lane < 32) {
            __builtin_nontemporal_store(table[p * 32 + lane],
                                        &out[row * 32 + lane]);
        }

        // rotate prefetched row in
        id2 = nid; mk2 = nmk;
    }
}

extern "C" void kernel_launch(void* const* d_in, const int* in_sizes, int n_in,
                              void* d_out, int out_size, void* d_ws, size_t ws_size,
                              hipStream_t stream) {
    const int*   ids   = (const int*)d_in[0];
    const int*   amask = (const int*)d_in[1];
    const float* W1    = (const float*)d_in[2];
    const float* b1    = (const float*)d_in[3];
    const float* W2    = (const float*)d_in[4];
    const float* b2    = (const float*)d_in[5];
    float* out   = (float*)d_out;
    float* table = (float*)d_ws;       // NPAIR*32*4 = 2.13 MB of ws

    const int B = in_sizes[0] / ROW_LEN;              // 262144

    const int tblThreads = NPAIR * 32;
    mlp_table_kernel<<<(tblThreads + 255) / 256, 256, 0, stream>>>(W1, b1, W2, b2, table);

    // persistent grid: 2048 blocks = 8 blocks/CU x 256 CUs; 8192 waves,
    // each wave owns B/8192 = 32 rows, depth-1 prefetch inside the loop.
    int blocks = (B + 3) / 4;
    if (blocks > 2048) blocks = 2048;
    rows_kernel<<<blocks, 256, 0, stream>>>(ids, amask, table, out, B);
}